// Round 8
// baseline (194.519 us; speedup 1.0000x reference)
//
#include <hip/hip_runtime.h>

#define AS1 __attribute__((address_space(1)))
#define AS3 __attribute__((address_space(3)))

typedef short short8 __attribute__((ext_vector_type(8)));
typedef float f32x16 __attribute__((ext_vector_type(16)));
typedef unsigned short ushort4v __attribute__((ext_vector_type(4)));

// Problem constants
#define BATCH 4096
#define IN_F 256
#define OUT_F 256
#define HYP 128
#define HX 129            // HYP + 1 (b2g folded in as extra channel, gain 1.0)
#define KP (HX * IN_F)    // 33024 shorts per V row
#define NGEMMP 32         // prep GEMM blocks (M-tile 128)
#define NVB 516           // V-build blocks (2048 cids each; 256*129*32 / 2048)

__device__ __forceinline__ float bf2f(unsigned short u) {
  unsigned v = ((unsigned)u) << 16;
  float f;
  __builtin_memcpy(&f, &v, 4);
  return f;
}
__device__ __forceinline__ unsigned short f2bf(float f) {
  unsigned u;
  __builtin_memcpy(&u, &f, 4);
  unsigned r = u + 0x7fffu + ((u >> 16) & 1u);  // RTNE
  return (unsigned short)(r >> 16);
}

__device__ __forceinline__ void gld_lds16(const unsigned short* g, unsigned short* s) {
  __builtin_amdgcn_global_load_lds((const AS1 unsigned int*)g, (AS3 unsigned int*)s, 16, 0, 0);
}

// ---------------------------------------------------------------------------
// k_trans: build bf16 transposed weight views so MFMA operands are
// k-contiguous.  W1T[n][k] (n<128: W1g^T, n>=128: W1b^T), W2bT[o][h].
// ---------------------------------------------------------------------------
__global__ __launch_bounds__(256) void k_trans(const float* __restrict__ W1g,
                                               const float* __restrict__ W1b,
                                               const float* __restrict__ W2b,
                                               unsigned short* __restrict__ W1T,
                                               unsigned short* __restrict__ W2bT) {
  const int t = threadIdx.x, b = blockIdx.x;
  if (b < 64) {
#pragma unroll
    for (int i = 0; i < 4; ++i) {
      const int e = b * 1024 + i * 256 + t;   // < 65536
      const int n = e >> 8, k = e & 255;
      const float v = (n < HYP) ? W1g[k * HYP + n] : W1b[k * HYP + (n - HYP)];
      W1T[e] = f2bf(v);
    }
  } else {
#pragma unroll
    for (int i = 0; i < 4; ++i) {
      const int e = (b - 64) * 1024 + i * 256 + t;  // < 32768
      const int o = e >> 7, h = e & 127;
      W2bT[e] = f2bf(W2b[h * OUT_F + o]);
    }
  }
}

// ---------------------------------------------------------------------------
// k_prep: blocks [0,NGEMMP): MFMA prep GEMMs, M-tile 128, 8 waves.
// blocks [NGEMMP, NGEMMP+NVB): V build.  (verified round-2 kernel, unchanged)
// ---------------------------------------------------------------------------
__global__ __launch_bounds__(512) void k_prep(
    const float* __restrict__ x,
    const float* __restrict__ b1g, const float* __restrict__ b1b,
    const float* __restrict__ b2b,
    const float* __restrict__ W2g, const float* __restrict__ b2g,
    const unsigned short* __restrict__ W1T, const unsigned short* __restrict__ W2bT,
    unsigned short* __restrict__ Vb, unsigned short* __restrict__ hgbT,
    unsigned short* __restrict__ xb, float* __restrict__ out) {
  __shared__ __align__(16) unsigned short xS[128 * 256];   // 64 KB, chunk^row&31 swizzle
  __shared__ __align__(16) unsigned short hbS[128 * 128];  // 32 KB, chunk^m&15 swizzle
  const int t = threadIdx.x;

  if (blockIdx.x >= NGEMMP) {
    const int base = (blockIdx.x - NGEMMP) * 2048 + t;
#pragma unroll
    for (int it = 0; it < 4; ++it) {
      const int cid = base + it * 512;
      const int ic = cid & 31;
      const int pair = cid >> 5;        // o*129 + h
      const int h = pair % HX;
      const int o = pair / HX;
      const float* src = (h < HYP) ? (W2g + (size_t)h * (OUT_F * IN_F) + o * IN_F + ic * 8)
                                   : (b2g + o * IN_F + ic * 8);
      const float4 v0 = ((const float4*)src)[0];
      const float4 v1 = ((const float4*)src)[1];
      uint4 pk;
      pk.x = (unsigned)f2bf(v0.x) | ((unsigned)f2bf(v0.y) << 16);
      pk.y = (unsigned)f2bf(v0.z) | ((unsigned)f2bf(v0.w) << 16);
      pk.z = (unsigned)f2bf(v1.x) | ((unsigned)f2bf(v1.y) << 16);
      pk.w = (unsigned)f2bf(v1.z) | ((unsigned)f2bf(v1.w) << 16);
      *(uint4*)(Vb + (size_t)o * KP + h * IN_F + ic * 8) = pk;
    }
    return;
  }

  const int lane = t & 63;
  const int w = t >> 6;            // 0..7
  const int l31 = lane & 31;
  const int hi = lane >> 5;
  const int m0 = blockIdx.x * 128;

#pragma unroll
  for (int j = 0; j < 16; ++j) {
    const int row = j * 8 + w;                       // 0..127, each once
    const float4 v = *(const float4*)(x + (size_t)(m0 + row) * IN_F + lane * 4);
    uint2 pk;
    pk.x = (unsigned)f2bf(v.x) | ((unsigned)f2bf(v.y) << 16);
    pk.y = (unsigned)f2bf(v.z) | ((unsigned)f2bf(v.w) << 16);
    *(uint2*)(xb + (size_t)(m0 + row) * IN_F + lane * 4) = pk;
    const int ch = lane >> 1, half = lane & 1;       // 16B chunk, 8B half
    *(uint2*)(&xS[row * 256 + ((ch ^ (row & 31))) * 8 + half * 4]) = pk;
  }
  __syncthreads();

  const int hA = w * 32 + l31;                       // 0..255 (g: <128, b: >=128)
  uint4 af[16];
#pragma unroll
  for (int kt = 0; kt < 16; ++kt)
    af[kt] = *(const uint4*)(W1T + (size_t)hA * 256 + kt * 16 + hi * 8);

  f32x16 zv;
#pragma unroll
  for (int i = 0; i < 16; ++i) zv[i] = 0.0f;
  f32x16 d0 = zv, d1 = zv, d2 = zv, d3 = zv;
#pragma unroll
  for (int kt = 0; kt < 16; ++kt) {
    const int pos = (kt * 2 + hi) ^ l31;             // (m&31) == l31 for all csub
    const short8 a = __builtin_bit_cast(short8, af[kt]);
#define G1STEP(CS, DD)                                                        \
    {                                                                         \
      const short8 bfrg = *(const short8*)(&xS[(CS * 32 + l31) * 256 + pos * 8]); \
      DD = __builtin_amdgcn_mfma_f32_32x32x16_bf16(a, bfrg, DD, 0, 0, 0);     \
    }
    G1STEP(0, d0) G1STEP(1, d1) G1STEP(2, d2) G1STEP(3, d3)
#undef G1STEP
  }

  if (w < 4) {
    float4 bq[4];
#pragma unroll
    for (int q = 0; q < 4; ++q)
      bq[q] = *(const float4*)(b1g + w * 32 + q * 8 + hi * 4);
#define EPI_G(CS, DD)                                                         \
    {                                                                         \
      const int mcol = m0 + CS * 32 + l31;                                    \
      _Pragma("unroll")                                                       \
      for (int g = 0; g < 16; ++g) {                                          \
        const int h = w * 32 + (g & 3) + 8 * (g >> 2) + 4 * hi;               \
        float v = DD[g] + ((const float*)&bq[g >> 2])[g & 3];                 \
        v = v > 0.f ? v : 0.f;                                                \
        hgbT[(size_t)h * BATCH + mcol] = f2bf(v);                             \
      }                                                                       \
    }
    EPI_G(0, d0) EPI_G(1, d1) EPI_G(2, d2) EPI_G(3, d3)
#undef EPI_G
  } else {
    float4 bq[4];
#pragma unroll
    for (int q = 0; q < 4; ++q)
      bq[q] = *(const float4*)(b1b + (w - 4) * 32 + q * 8 + hi * 4);
#define EPI_B(CS, DD)                                                         \
    {                                                                         \
      const int m = CS * 32 + l31;                                            \
      _Pragma("unroll")                                                       \
      for (int q = 0; q < 4; ++q) {                                           \
        float v0 = DD[q * 4 + 0] + ((const float*)&bq[q])[0];                 \
        float v1 = DD[q * 4 + 1] + ((const float*)&bq[q])[1];                 \
        float v2 = DD[q * 4 + 2] + ((const float*)&bq[q])[2];                 \
        float v3 = DD[q * 4 + 3] + ((const float*)&bq[q])[3];                 \
        v0 = v0 > 0.f ? v0 : 0.f; v1 = v1 > 0.f ? v1 : 0.f;                   \
        v2 = v2 > 0.f ? v2 : 0.f; v3 = v3 > 0.f ? v3 : 0.f;                   \
        uint2 pk;                                                             \
        pk.x = (unsigned)f2bf(v0) | ((unsigned)f2bf(v1) << 16);               \
        pk.y = (unsigned)f2bf(v2) | ((unsigned)f2bf(v3) << 16);               \
        const int chunk = (w - 4) * 4 + q;                                    \
        *(uint2*)(&hbS[m * 128 + ((chunk ^ (m & 15))) * 8 + hi * 4]) = pk;    \
      }                                                                       \
    }
    EPI_B(0, d0) EPI_B(1, d1) EPI_B(2, d2) EPI_B(3, d3)
#undef EPI_B
  }
  __syncthreads();

  const int msub = w & 3, oh = w >> 2;
  const int mA = msub * 32 + l31;
  f32x16 e0 = zv, e1 = zv, e2 = zv, e3 = zv;
#pragma unroll
  for (int kt = 0; kt < 8; ++kt) {
    const int pos = (kt * 2 + hi) ^ (mA & 15);
    const short8 a = *(const short8*)(&hbS[mA * 128 + pos * 8]);
#define G2STEP(OS, EE)                                                        \
    {                                                                         \
      const int orow = oh * 128 + OS * 32 + l31;                              \
      const short8 bb = *(const short8*)(W2bT + (size_t)orow * 128 + kt * 16 + hi * 8); \
      EE = __builtin_amdgcn_mfma_f32_32x32x16_bf16(a, bb, EE, 0, 0, 0);       \
    }
    G2STEP(0, e0) G2STEP(1, e1) G2STEP(2, e2) G2STEP(3, e3)
#undef G2STEP
  }
#define EPI2(OS, EE)                                                          \
  {                                                                           \
    const int o = oh * 128 + OS * 32 + l31;                                   \
    const float bo = b2b[o];                                                  \
    _Pragma("unroll")                                                         \
    for (int g = 0; g < 16; ++g) {                                            \
      const int m = m0 + msub * 32 + (g & 3) + 8 * (g >> 2) + 4 * hi;         \
      out[(size_t)m * OUT_F + o] = EE[g] + bo;                                \
    }                                                                         \
  }
  EPI2(0, e0) EPI2(1, e1) EPI2(2, e2) EPI2(3, e3)
#undef EPI2
}

// ---------------------------------------------------------------------------
// k_gemm: out[b,o] += sum_h hg[b,h] * (sum_i V[o][h*256+i]*x[b,i])
// Round-2 verified inner structure (double-buffer + issue-ahead +
// __syncthreads). NEW geometry to fit the whole wave state in ARCH VGPRs
// (<=128) and reach 4 waves/SIMD:
//   block = 256 thr / 4 waves; wave tile 32m x 32o (xf[16] = 64 VGPR, one
//   acc + one ah chain); M-tile 128, N-tile 32, z-split 8 (nh = 16..17).
//   LDS = 2 x 16 KB dbuf + 4.3 KB hg = ~37 KB -> 4 blocks/CU.
// Rationale: VALUBusy 17.6% at round 7 => ~280 VALU inst/wave/round, ~160
// more than source-level count -> the 128-VGPR xf array was living in AGPRs
// with v_accvgpr_read shuttles on the MFMA operand path (VGPR_Count 120 <
// live set in every prior config). 64-reg xf + <=128 total removes the
// shuttle AND doubles waves/SIMD for latency hiding.
// ---------------------------------------------------------------------------
__global__ __launch_bounds__(256, 4)
void k_gemm(const unsigned short* __restrict__ Vb,
            const unsigned short* __restrict__ hgbT,
            const unsigned short* __restrict__ xb,
            float* __restrict__ out) {
  __shared__ __align__(16) unsigned short Bl[2][32 * 256];   // 2 x 16 KB
  __shared__ __align__(16) unsigned short hgs[17 * 128];     // 4.25 KB [h_local][m]
  const int tid = threadIdx.x;
  const int lane = tid & 63;
  const int wave = tid >> 6;        // 0..3, m-subtile
  const int l31 = lane & 31;
  const int hi = lane >> 5;

  // XCD-aware decode: 2048 blocks; group g = (o-tile, z) pins to XCD g&7.
  const int bid = blockIdx.x;       // 0..2047
  const int c = bid & 7;
  const int t2 = bid >> 3;          // 0..255
  const int xm = t2 & 31;           // m-block (32)
  const int g8 = t2 >> 5;           // 0..7
  const int grp = c + 8 * g8;       // 0..63
  const int yo = grp & 7;           // o-tile (8)
  const int z = grp >> 3;           // z (8)

  const int m0 = xm * 128;
  const int o0 = yo * 32;
  const int hBeg = (z * HX) >> 3;
  const int hEnd = ((z + 1) * HX) >> 3;
  const int nh = hEnd - hBeg;   // 16 x7, 17

  // ---- stage hg tile [h_local][m] bf16 (h==128 -> 1.0) ----
  for (int idx = tid; idx < nh * 128; idx += 256) {
    const int hl = idx >> 7;
    const int hh = hBeg + hl;
    hgs[idx] = (hh == HYP) ? (unsigned short)0x3F80
                           : hgbT[(size_t)hh * BATCH + m0 + (idx & 127)];
  }

  // ---- preload A fragments (32 m-rows x 16 k16-tiles = 64 VGPR) ----
  const int mrow = m0 + wave * 32 + l31;
  uint4 xf[16];
#pragma unroll
  for (int j = 0; j < 16; ++j)
    xf[j] = *(const uint4*)(xb + (size_t)mrow * IN_F + j * 16 + hi * 8);

  // ---- staging geometry: 1024 chunks of 16B per round, 4 per thread ----
  const int nB = tid >> 5;            // base row (rows nB + 8j, j<4)
  const int p5 = tid & 31;            // stored position within row
  const int cs = p5 ^ (nB & 7);       // source chunk (XOR swizzle, self-inverse)
  const unsigned short* gsrc = Vb + (size_t)(o0 + nB) * KP + cs * 8 + (size_t)hBeg * IN_F;

  f32x16 zv;
#pragma unroll
  for (int i = 0; i < 16; ++i) zv[i] = 0.0f;
  f32x16 acc = zv, ah = zv;

  // prologue: stage round 0 into buf 0 (rows nB + 8j)
#pragma unroll
  for (int j = 0; j < 4; ++j)
    gld_lds16(gsrc + (size_t)j * 8 * KP, &Bl[0][((size_t)tid + 256 * j) * 8]);
  __syncthreads();

  for (int r = 0; r < nh; ++r) {
    const int buf = r & 1;
    if (r + 1 < nh) {  // issue next round's staging ahead of compute
      const unsigned short* gs = gsrc + (size_t)(r + 1) * IN_F;
#pragma unroll
      for (int j = 0; j < 4; ++j)
        gld_lds16(gs + (size_t)j * 8 * KP, &Bl[buf ^ 1][((size_t)tid + 256 * j) * 8]);
    }
    const unsigned short* bp = &Bl[buf][0];
#pragma unroll
    for (int kt = 0; kt < 16; ++kt) {
      const int c0 = kt * 2 + hi;
      const int pr = c0 ^ (l31 & 7);
      const short8 b0 = *(const short8*)(bp + l31 * 256 + pr * 8);
      const short8 a0 = __builtin_bit_cast(short8, xf[kt]);
      if (kt == 0)  // C = 0: kills the per-round ah reset
        ah = __builtin_amdgcn_mfma_f32_32x32x16_bf16(a0, b0, zv, 0, 0, 0);
      else
        ah = __builtin_amdgcn_mfma_f32_32x32x16_bf16(a0, b0, ah, 0, 0, 0);
    }
    // flush: acc += hg * ah (linearity: hg scale applied post-MFMA)
#pragma unroll
    for (int q = 0; q < 4; ++q) {
      const ushort4v v0 = *(const ushort4v*)&hgs[r * 128 + wave * 32 + 4 * hi + q * 8];
#pragma unroll
      for (int e = 0; e < 4; ++e)
        acc[q * 4 + e] += bf2f(v0[e]) * ah[q * 4 + e];
    }
    __syncthreads();  // drains next-buf loads (issued a round ago) + buf reuse
  }

  // epilogue: atomic accumulate (8 h-splits per output)
  const int mb = m0 + wave * 32 + 4 * hi;
  const int col = o0 + l31;
#pragma unroll
  for (int g = 0; g < 16; ++g) {
    const int row0 = mb + (g & 3) + 8 * (g >> 2);
    atomicAdd(&out[(size_t)row0 * OUT_F + col], acc[g]);
  }
}

// ---------------------------------------------------------------------------
extern "C" void kernel_launch(void* const* d_in, const int* in_sizes, int n_in,
                              void* d_out, int out_size, void* d_ws, size_t ws_size,
                              hipStream_t stream) {
  const float* x = (const float*)d_in[0];
  const float* W1g = (const float*)d_in[1];
  const float* b1g = (const float*)d_in[2];
  const float* W2g = (const float*)d_in[3];
  const float* b2g = (const float*)d_in[4];
  const float* W1b = (const float*)d_in[5];
  const float* b1b = (const float*)d_in[6];
  const float* W2b = (const float*)d_in[7];
  const float* b2b = (const float*)d_in[8];
  float* out = (float*)d_out;

  char* ws = (char*)d_ws;
  const size_t szV = (size_t)OUT_F * KP * 2;        // 16,908,288
  const size_t szHg = (size_t)HYP * BATCH * 2;      //  1,048,576
  const size_t szXb = (size_t)BATCH * IN_F * 2;     //  2,097,152
  const size_t szW1T = (size_t)256 * 256 * 2;       //    131,072
  unsigned short* Vb = (unsigned short*)ws;
  unsigned short* hgbT = (unsigned short*)(ws + szV);
  unsigned short* xb = (unsigned short*)(ws + szV + szHg);
  unsigned short* W1T = (unsigned short*)(ws + szV + szHg + szXb);
  unsigned short* W2bT = (unsigned short*)(ws + szV + szHg + szXb + szW1T);

  hipLaunchKernelGGL(k_trans, dim3(96), dim3(256), 0, stream, W1g, W1b, W2b, W1T, W2bT);
  hipLaunchKernelGGL(k_prep, dim3(NGEMMP + NVB), dim3(512), 0, stream,
                     x, b1g, b1b, b2b, W2g, b2g, W1T, W2bT, Vb, hgbT, xb, out);
  hipLaunchKernelGGL(k_gemm, dim3(2048), dim3(256), 0, stream, Vb, hgbT, xb, out);
}

// Round 9
// 190.281 us; speedup vs baseline: 1.0223x; 1.0223x over previous
//
#include <hip/hip_runtime.h>

#define AS1 __attribute__((address_space(1)))
#define AS3 __attribute__((address_space(3)))

typedef short short8 __attribute__((ext_vector_type(8)));
typedef float f32x16 __attribute__((ext_vector_type(16)));
typedef unsigned short ushort4v __attribute__((ext_vector_type(4)));

// Problem constants
#define BATCH 4096
#define IN_F 256
#define OUT_F 256
#define HYP 128
#define HX 129            // HYP + 1 (b2g folded in as extra channel, gain 1.0)
#define KP (HX * IN_F)    // 33024 shorts per V row
#define NGEMMP 32         // prep GEMM blocks (M-tile 128)
#define NVB 516           // V-build blocks (2048 cids each; 256*129*32 / 2048)

__device__ __forceinline__ float bf2f(unsigned short u) {
  unsigned v = ((unsigned)u) << 16;
  float f;
  __builtin_memcpy(&f, &v, 4);
  return f;
}
__device__ __forceinline__ unsigned short f2bf(float f) {
  unsigned u;
  __builtin_memcpy(&u, &f, 4);
  unsigned r = u + 0x7fffu + ((u >> 16) & 1u);  // RTNE
  return (unsigned short)(r >> 16);
}

__device__ __forceinline__ void gld_lds16(const unsigned short* g, unsigned short* s) {
  __builtin_amdgcn_global_load_lds((const AS1 unsigned int*)g, (AS3 unsigned int*)s, 16, 0, 0);
}

// ---------------------------------------------------------------------------
// k_trans: build bf16 transposed weight views so MFMA operands are
// k-contiguous.  W1T[n][k] (n<128: W1g^T, n>=128: W1b^T), W2bT[o][h].
// ---------------------------------------------------------------------------
__global__ __launch_bounds__(256) void k_trans(const float* __restrict__ W1g,
                                               const float* __restrict__ W1b,
                                               const float* __restrict__ W2b,
                                               unsigned short* __restrict__ W1T,
                                               unsigned short* __restrict__ W2bT) {
  const int t = threadIdx.x, b = blockIdx.x;
  if (b < 64) {
#pragma unroll
    for (int i = 0; i < 4; ++i) {
      const int e = b * 1024 + i * 256 + t;   // < 65536
      const int n = e >> 8, k = e & 255;
      const float v = (n < HYP) ? W1g[k * HYP + n] : W1b[k * HYP + (n - HYP)];
      W1T[e] = f2bf(v);
    }
  } else {
#pragma unroll
    for (int i = 0; i < 4; ++i) {
      const int e = (b - 64) * 1024 + i * 256 + t;  // < 32768
      const int o = e >> 7, h = e & 127;
      W2bT[e] = f2bf(W2b[h * OUT_F + o]);
    }
  }
}

// ---------------------------------------------------------------------------
// k_prep: blocks [0,NGEMMP): MFMA prep GEMMs, M-tile 128, 8 waves.
// blocks [NGEMMP, NGEMMP+NVB): V build.  (verified round-2 kernel, unchanged)
// ---------------------------------------------------------------------------
__global__ __launch_bounds__(512) void k_prep(
    const float* __restrict__ x,
    const float* __restrict__ b1g, const float* __restrict__ b1b,
    const float* __restrict__ b2b,
    const float* __restrict__ W2g, const float* __restrict__ b2g,
    const unsigned short* __restrict__ W1T, const unsigned short* __restrict__ W2bT,
    unsigned short* __restrict__ Vb, unsigned short* __restrict__ hgbT,
    unsigned short* __restrict__ xb, float* __restrict__ out) {
  __shared__ __align__(16) unsigned short xS[128 * 256];   // 64 KB, chunk^row&31 swizzle
  __shared__ __align__(16) unsigned short hbS[128 * 128];  // 32 KB, chunk^m&15 swizzle
  const int t = threadIdx.x;

  if (blockIdx.x >= NGEMMP) {
    const int base = (blockIdx.x - NGEMMP) * 2048 + t;
#pragma unroll
    for (int it = 0; it < 4; ++it) {
      const int cid = base + it * 512;
      const int ic = cid & 31;
      const int pair = cid >> 5;        // o*129 + h
      const int h = pair % HX;
      const int o = pair / HX;
      const float* src = (h < HYP) ? (W2g + (size_t)h * (OUT_F * IN_F) + o * IN_F + ic * 8)
                                   : (b2g + o * IN_F + ic * 8);
      const float4 v0 = ((const float4*)src)[0];
      const float4 v1 = ((const float4*)src)[1];
      uint4 pk;
      pk.x = (unsigned)f2bf(v0.x) | ((unsigned)f2bf(v0.y) << 16);
      pk.y = (unsigned)f2bf(v0.z) | ((unsigned)f2bf(v0.w) << 16);
      pk.z = (unsigned)f2bf(v1.x) | ((unsigned)f2bf(v1.y) << 16);
      pk.w = (unsigned)f2bf(v1.z) | ((unsigned)f2bf(v1.w) << 16);
      *(uint4*)(Vb + (size_t)o * KP + h * IN_F + ic * 8) = pk;
    }
    return;
  }

  const int lane = t & 63;
  const int w = t >> 6;            // 0..7
  const int l31 = lane & 31;
  const int hi = lane >> 5;
  const int m0 = blockIdx.x * 128;

#pragma unroll
  for (int j = 0; j < 16; ++j) {
    const int row = j * 8 + w;                       // 0..127, each once
    const float4 v = *(const float4*)(x + (size_t)(m0 + row) * IN_F + lane * 4);
    uint2 pk;
    pk.x = (unsigned)f2bf(v.x) | ((unsigned)f2bf(v.y) << 16);
    pk.y = (unsigned)f2bf(v.z) | ((unsigned)f2bf(v.w) << 16);
    *(uint2*)(xb + (size_t)(m0 + row) * IN_F + lane * 4) = pk;
    const int ch = lane >> 1, half = lane & 1;       // 16B chunk, 8B half
    *(uint2*)(&xS[row * 256 + ((ch ^ (row & 31))) * 8 + half * 4]) = pk;
  }
  __syncthreads();

  const int hA = w * 32 + l31;                       // 0..255 (g: <128, b: >=128)
  uint4 af[16];
#pragma unroll
  for (int kt = 0; kt < 16; ++kt)
    af[kt] = *(const uint4*)(W1T + (size_t)hA * 256 + kt * 16 + hi * 8);

  f32x16 zv;
#pragma unroll
  for (int i = 0; i < 16; ++i) zv[i] = 0.0f;
  f32x16 d0 = zv, d1 = zv, d2 = zv, d3 = zv;
#pragma unroll
  for (int kt = 0; kt < 16; ++kt) {
    const int pos = (kt * 2 + hi) ^ l31;             // (m&31) == l31 for all csub
    const short8 a = __builtin_bit_cast(short8, af[kt]);
#define G1STEP(CS, DD)                                                        \
    {                                                                         \
      const short8 bfrg = *(const short8*)(&xS[(CS * 32 + l31) * 256 + pos * 8]); \
      DD = __builtin_amdgcn_mfma_f32_32x32x16_bf16(a, bfrg, DD, 0, 0, 0);     \
    }
    G1STEP(0, d0) G1STEP(1, d1) G1STEP(2, d2) G1STEP(3, d3)
#undef G1STEP
  }

  if (w < 4) {
    float4 bq[4];
#pragma unroll
    for (int q = 0; q < 4; ++q)
      bq[q] = *(const float4*)(b1g + w * 32 + q * 8 + hi * 4);
#define EPI_G(CS, DD)                                                         \
    {                                                                         \
      const int mcol = m0 + CS * 32 + l31;                                    \
      _Pragma("unroll")                                                       \
      for (int g = 0; g < 16; ++g) {                                          \
        const int h = w * 32 + (g & 3) + 8 * (g >> 2) + 4 * hi;               \
        float v = DD[g] + ((const float*)&bq[g >> 2])[g & 3];                 \
        v = v > 0.f ? v : 0.f;                                                \
        hgbT[(size_t)h * BATCH + mcol] = f2bf(v);                             \
      }                                                                       \
    }
    EPI_G(0, d0) EPI_G(1, d1) EPI_G(2, d2) EPI_G(3, d3)
#undef EPI_G
  } else {
    float4 bq[4];
#pragma unroll
    for (int q = 0; q < 4; ++q)
      bq[q] = *(const float4*)(b1b + (w - 4) * 32 + q * 8 + hi * 4);
#define EPI_B(CS, DD)                                                         \
    {                                                                         \
      const int m = CS * 32 + l31;                                            \
      _Pragma("unroll")                                                       \
      for (int q = 0; q < 4; ++q) {                                           \
        float v0 = DD[q * 4 + 0] + ((const float*)&bq[q])[0];                 \
        float v1 = DD[q * 4 + 1] + ((const float*)&bq[q])[1];                 \
        float v2 = DD[q * 4 + 2] + ((const float*)&bq[q])[2];                 \
        float v3 = DD[q * 4 + 3] + ((const float*)&bq[q])[3];                 \
        v0 = v0 > 0.f ? v0 : 0.f; v1 = v1 > 0.f ? v1 : 0.f;                   \
        v2 = v2 > 0.f ? v2 : 0.f; v3 = v3 > 0.f ? v3 : 0.f;                   \
        uint2 pk;                                                             \
        pk.x = (unsigned)f2bf(v0) | ((unsigned)f2bf(v1) << 16);               \
        pk.y = (unsigned)f2bf(v2) | ((unsigned)f2bf(v3) << 16);               \
        const int chunk = (w - 4) * 4 + q;                                    \
        *(uint2*)(&hbS[m * 128 + ((chunk ^ (m & 15))) * 8 + hi * 4]) = pk;    \
      }                                                                       \
    }
    EPI_B(0, d0) EPI_B(1, d1) EPI_B(2, d2) EPI_B(3, d3)
#undef EPI_B
  }
  __syncthreads();

  const int msub = w & 3, oh = w >> 2;
  const int mA = msub * 32 + l31;
  f32x16 e0 = zv, e1 = zv, e2 = zv, e3 = zv;
#pragma unroll
  for (int kt = 0; kt < 8; ++kt) {
    const int pos = (kt * 2 + hi) ^ (mA & 15);
    const short8 a = *(const short8*)(&hbS[mA * 128 + pos * 8]);
#define G2STEP(OS, EE)                                                        \
    {                                                                         \
      const int orow = oh * 128 + OS * 32 + l31;                              \
      const short8 bb = *(const short8*)(W2bT + (size_t)orow * 128 + kt * 16 + hi * 8); \
      EE = __builtin_amdgcn_mfma_f32_32x32x16_bf16(a, bb, EE, 0, 0, 0);       \
    }
    G2STEP(0, e0) G2STEP(1, e1) G2STEP(2, e2) G2STEP(3, e3)
#undef G2STEP
  }
#define EPI2(OS, EE)                                                          \
  {                                                                           \
    const int o = oh * 128 + OS * 32 + l31;                                   \
    const float bo = b2b[o];                                                  \
    _Pragma("unroll")                                                         \
    for (int g = 0; g < 16; ++g) {                                            \
      const int m = m0 + msub * 32 + (g & 3) + 8 * (g >> 2) + 4 * hi;         \
      out[(size_t)m * OUT_F + o] = EE[g] + bo;                                \
    }                                                                         \
  }
  EPI2(0, e0) EPI2(1, e1) EPI2(2, e2) EPI2(3, e3)
#undef EPI2
}

// ---------------------------------------------------------------------------
// k_gemm: out[b,o] += sum_h hg[b,h] * (sum_i V[o][h*256+i]*x[b,i])
// Round-7 verified kernel (256 thr / 4 waves, M-tile 128, N=64, 2 blocks/CU,
// dbuf + issue-ahead + __syncthreads) with ONE fix: the chunk swizzle now
// uses 4 row bits (was 3). Old: pr = c0 ^ (l31&7) left the 32 lanes on 8
// chunk values while the row term (512B stride) contributes 0 mod 32 banks
// -> structural 4-way bank conflict on every B-read (4.2M extra cyc, m136:
// 1.58x). New: stored[row][p] = V[row][p ^ (row&15)]; read pr = c0 ^
// (l31&15) -> 2 lanes/chunk (2-way = free). Write side: row = nB+8j, so
// even j stages from chunk p5^nB, odd j from p5^nB^8 (two src pointers).
// ---------------------------------------------------------------------------
__global__ __launch_bounds__(256, 2)
void k_gemm(const unsigned short* __restrict__ Vb,
            const unsigned short* __restrict__ hgbT,
            const unsigned short* __restrict__ xb,
            float* __restrict__ out) {
  __shared__ __align__(16) unsigned short Bl[2][64 * 256];   // 2 x 32 KB
  __shared__ __align__(16) unsigned short hgs[33 * 128];     // 8.25 KB [h_local][m] bf16
  const int tid = threadIdx.x;
  const int lane = tid & 63;
  const int wave = tid >> 6;        // 0..3
  const int l31 = lane & 31;
  const int hi = lane >> 5;
  const int wm = wave & 1;          // m-group (64 rows)
  const int wo = wave >> 1;         // o-half (32 cols)

  // XCD-aware decode: 512 blocks; group g = (o-tile, z) pins to XCD g&7.
  const int bid = blockIdx.x;       // 0..511
  const int c = bid & 7;
  const int t2 = bid >> 3;          // 0..63
  const int xm = t2 & 31;           // m-block (32 of them)
  const int g8 = t2 >> 5;           // 0..1
  const int grp = c + 8 * g8;       // 0..15
  const int yo = grp & 3;
  const int z = grp >> 2;

  const int m0 = xm * 128;
  const int o0 = yo * 64;
  const int hBeg = (z * HX) >> 2;
  const int hEnd = ((z + 1) * HX) >> 2;
  const int nh = hEnd - hBeg;   // 32,32,32,33

  // ---- stage hg tile [h_local][m] bf16 (h==128 -> 1.0) ----
  for (int idx = tid; idx < nh * 128; idx += 256) {
    const int hl = idx >> 7;
    const int hh = hBeg + hl;
    hgs[idx] = (hh == HYP) ? (unsigned short)0x3F80
                           : hgbT[(size_t)hh * BATCH + m0 + (idx & 127)];
  }

  // ---- preload A fragments (2 m-subtiles x 16 k16-tiles), persistent ----
  const int mrow0 = m0 + wm * 64 + l31;
  const int mrow1 = mrow0 + 32;
  uint4 xf0[16], xf1[16];
#pragma unroll
  for (int j = 0; j < 16; ++j) {
    xf0[j] = *(const uint4*)(xb + (size_t)mrow0 * IN_F + j * 16 + hi * 8);
    xf1[j] = *(const uint4*)(xb + (size_t)mrow1 * IN_F + j * 16 + hi * 8);
  }

  // ---- staging geometry: 2048 chunks of 16B per round, 8 per thread ----
  // stored[row][p5] = V[row][p5 ^ (row & 15)]; row = nB + 8j ->
  // row&15 = nB | (8*(j&1)): even j from cs0 = p5^nB, odd j from cs0^8.
  const int nB = tid >> 5;            // base row (rows nB + 8j)
  const int p5 = tid & 31;            // stored position within row
  const int cs0 = p5 ^ nB;            // source chunk, even j
  const unsigned short* gsrc0 = Vb + (size_t)(o0 + nB) * KP + cs0 * 8 + (size_t)hBeg * IN_F;
  const unsigned short* gsrc1 = Vb + (size_t)(o0 + nB) * KP + (cs0 ^ 8) * 8 + (size_t)hBeg * IN_F;

  f32x16 zv;
#pragma unroll
  for (int i = 0; i < 16; ++i) zv[i] = 0.0f;
  f32x16 acc0 = zv, acc1 = zv;
  f32x16 ah0 = zv, ah1 = zv;

  // prologue: stage round 0 into buf 0 (rows nB + 8j)
#pragma unroll
  for (int j = 0; j < 8; ++j)
    gld_lds16(((j & 1) ? gsrc1 : gsrc0) + (size_t)j * 8 * KP,
              &Bl[0][((size_t)tid + 256 * j) * 8]);
  __syncthreads();

  const int rowb = wo * 32 + l31;
  for (int r = 0; r < nh; ++r) {
    const int buf = r & 1;
    if (r + 1 < nh) {  // issue next round's staging ahead of compute
      const size_t roff = (size_t)(r + 1) * IN_F;
#pragma unroll
      for (int j = 0; j < 8; ++j)
        gld_lds16(((j & 1) ? gsrc1 : gsrc0) + roff + (size_t)j * 8 * KP,
                  &Bl[buf ^ 1][((size_t)tid + 256 * j) * 8]);
    }
    const unsigned short* bp = &Bl[buf][0];
#pragma unroll
    for (int ic = 0; ic < 4; ++ic) {
#pragma unroll
      for (int t = 0; t < 4; ++t) {
        const int c0 = ic * 8 + t * 2 + hi;
        const int pr = c0 ^ (l31 & 15);          // 4-bit swizzle: 2-way = free
        const short8 b0 = *(const short8*)(bp + rowb * 256 + pr * 8);
        const short8 a0 = __builtin_bit_cast(short8, xf0[ic * 4 + t]);
        const short8 a1 = __builtin_bit_cast(short8, xf1[ic * 4 + t]);
        if (ic == 0 && t == 0) {  // C = 0: kills the per-round ah reset
          ah0 = __builtin_amdgcn_mfma_f32_32x32x16_bf16(a0, b0, zv, 0, 0, 0);
          ah1 = __builtin_amdgcn_mfma_f32_32x32x16_bf16(a1, b0, zv, 0, 0, 0);
        } else {
          ah0 = __builtin_amdgcn_mfma_f32_32x32x16_bf16(a0, b0, ah0, 0, 0, 0);
          ah1 = __builtin_amdgcn_mfma_f32_32x32x16_bf16(a1, b0, ah1, 0, 0, 0);
        }
      }
    }
    // flush: acc += hg * ah (linearity: hg scale applied post-MFMA)
#pragma unroll
    for (int q = 0; q < 4; ++q) {
      const ushort4v v0 = *(const ushort4v*)&hgs[r * 128 + wm * 64 + 4 * hi + q * 8];
      const ushort4v v1 = *(const ushort4v*)&hgs[r * 128 + wm * 64 + 32 + 4 * hi + q * 8];
#pragma unroll
      for (int e = 0; e < 4; ++e) {
        acc0[q * 4 + e] += bf2f(v0[e]) * ah0[q * 4 + e];
        acc1[q * 4 + e] += bf2f(v1[e]) * ah1[q * 4 + e];
      }
    }
    __syncthreads();  // drains next-buf loads (issued a round ago) + buf reuse
  }

  // epilogue: atomic accumulate (4 h-splits per output)
  const int mb = m0 + wm * 64 + 4 * hi;
  const int col = o0 + wo * 32 + l31;
#pragma unroll
  for (int g = 0; g < 16; ++g) {
    const int row0 = mb + (g & 3) + 8 * (g >> 2);
    atomicAdd(&out[(size_t)row0 * OUT_F + col], acc0[g]);
    atomicAdd(&out[(size_t)(row0 + 32) * OUT_F + col], acc1[g]);
  }
}

// ---------------------------------------------------------------------------
extern "C" void kernel_launch(void* const* d_in, const int* in_sizes, int n_in,
                              void* d_out, int out_size, void* d_ws, size_t ws_size,
                              hipStream_t stream) {
  const float* x = (const float*)d_in[0];
  const float* W1g = (const float*)d_in[1];
  const float* b1g = (const float*)d_in[2];
  const float* W2g = (const float*)d_in[3];
  const float* b2g = (const float*)d_in[4];
  const float* W1b = (const float*)d_in[5];
  const float* b1b = (const float*)d_in[6];
  const float* W2b = (const float*)d_in[7];
  const float* b2b = (const float*)d_in[8];
  float* out = (float*)d_out;

  char* ws = (char*)d_ws;
  const size_t szV = (size_t)OUT_F * KP * 2;        // 16,908,288
  const size_t szHg = (size_t)HYP * BATCH * 2;      //  1,048,576
  const size_t szXb = (size_t)BATCH * IN_F * 2;     //  2,097,152
  const size_t szW1T = (size_t)256 * 256 * 2;       //    131,072
  unsigned short* Vb = (unsigned short*)ws;
  unsigned short* hgbT = (unsigned short*)(ws + szV);
  unsigned short* xb = (unsigned short*)(ws + szV + szHg);
  unsigned short* W1T = (unsigned short*)(ws + szV + szHg + szXb);
  unsigned short* W2bT = (unsigned short*)(ws + szV + szHg + szXb + szW1T);

  hipLaunchKernelGGL(k_trans, dim3(96), dim3(256), 0, stream, W1g, W1b, W2b, W1T, W2bT);
  hipLaunchKernelGGL(k_prep, dim3(NGEMMP + NVB), dim3(512), 0, stream,
                     x, b1g, b1b, b2b, W2g, b2g, W1T, W2bT, Vb, hgbT, xb, out);
  hipLaunchKernelGGL(k_gemm, dim3(512), dim3(256), 0, stream, Vb, hgbT, xb, out);
}